// Round 3
// baseline (562.628 us; speedup 1.0000x reference)
//
#include <hip/hip_runtime.h>

#define NEDGES 20000
#define KMAX 16
#define NTRIP (NEDGES*KMAX)
#define EMB 128
#define INTERM 64
#define NSPH 7
#define UNITS 128
#define MT_TOTAL 1250            // 16-edge M-tiles
#define KSTEPS 256               // K = 8192 / 32
#define NSLICE 4                 // split-K factor
#define MCHUNKS 313              // ceil(1250/4) m-tile quads
#define PROWS 20032              // padded edge rows in P

typedef __attribute__((ext_vector_type(8))) short short8;
typedef __attribute__((ext_vector_type(4))) float floatx4;

__device__ __forceinline__ unsigned bf16pair(float a, float b) {
    unsigned ua = __float_as_uint(a), ub = __float_as_uint(b);
    ua = (ua + 0x7fffu + ((ua >> 16) & 1u)) >> 16;
    ub = (ub + 0x7fffu + ((ub >> 16) & 1u)) & 0xffff0000u;
    return ua | ub;
}
__device__ __forceinline__ unsigned short bf16rne(float a) {
    unsigned u = __float_as_uint(a);
    return (unsigned short)((u + 0x7fffu + ((u >> 16) & 1u)) >> 16);
}

// async global->LDS 16B copy (lds dest must be uniform-base + lane*16 in wave order)
__device__ __forceinline__ void gload_lds16(const uint4* g, uint4* l) {
    __builtin_amdgcn_global_load_lds(
        (const __attribute__((address_space(1))) unsigned int*)(unsigned long long)(size_t)g,
        (__attribute__((address_space(3))) unsigned int*)(unsigned long long)(size_t)l,
        16, 0, 0);
}

__global__ void scatter_inv(const int* __restrict__ idr, const int* __restrict__ kix,
                            int* __restrict__ inv) {
    int t = blockIdx.x * 256 + threadIdx.x;
    if (t < NTRIP) {
        int e = idr[t], k = kix[t];
        if ((unsigned)e < NEDGES && (unsigned)k < KMAX)
            inv[e * KMAX + k] = t;
    }
}

// weight (emb, interm, o) fp32 -> bf16 MFMA B-fragment order.
// uint4 idx = (nt*256 + ks)*64 + lane; elem j: k = ks*32 + (lane>>4)*8 + j,
// o = nt*16 + (lane&15); k = i*128 + emb.
__global__ void build_w2f(const float* __restrict__ w, uint4* __restrict__ w2f) {
    int idx  = blockIdx.x * 256 + threadIdx.x;
    int lane = idx & 63;
    int ks   = (idx >> 6) & 255;
    int nt   = idx >> 14;
    int o  = nt * 16 + (lane & 15);
    int kb = ks * 32 + (lane >> 4) * 8;
    unsigned pk[4];
#pragma unroll
    for (int jj = 0; jj < 4; ++jj) {
        int k0 = kb + 2 * jj;
        int i0 = k0 >> 7, e0 = k0 & 127;
        int i1 = (k0 + 1) >> 7, e1 = (k0 + 1) & 127;
        float f0 = w[((size_t)e0 * INTERM + i0) * UNITS + o];
        float f1 = w[((size_t)e1 * INTERM + i1) * UNITS + o];
        pk[jj] = bf16pair(f0, f1);
    }
    w2f[idx] = make_uint4(pk[0], pk[1], pk[2], pk[3]);
}

// build_a: block = one 16-edge M-tile. thread identity: edge = tid&15, oct = tid>>4.
// A-frag uint4 idx = (mt*256 + i*4 + (oct>>2))*64 + lane, lane = (oct&3)*16 + edge = tid&63
// -> per-wave stores are contiguous 1KB rows.
__global__ __launch_bounds__(256)
void build_a(const float* __restrict__ rbf, const float* __restrict__ sph,
             const float* __restrict__ m, const int* __restrict__ inv,
             uint4* __restrict__ aw) {
    __shared__ float m_s[2][16][132];            // 16896 B (stride 132: 2-way banks)
    __shared__ float sph_s[112][16];             // 7168 B, [s*16+k][edge]
    __shared__ unsigned short rbf_s[16][520];    // 16640 B, [edge][i*8+s], 8-padded
    __shared__ int inv_s[256];                   // [edge*16+k]

    const int tid = threadIdx.x;
    const int mt  = blockIdx.x;
    const size_t e0 = (size_t)mt * 16;
    const int edge = tid & 15, oct = tid >> 4;

    inv_s[tid] = inv[e0 * 16 + tid];
    // sph transpose-stage: [e][s*16+k] -> [s*16+k][e]
    for (int j = tid; j < 16 * 112; j += 256) {
        int e = j / 112, r = j - e * 112;
        sph_s[r][e] = sph[e0 * 112 + j];
    }
    // rbf -> bf16, padded rows of 8 per i (coalesced float4 reads)
    {
        const float4* rg = (const float4*)(rbf + e0 * 448);
        for (int j = tid; j < 16 * 112; j += 256) {
            int e = j / 112, rem = j - e * 112;
            float4 v = rg[j];
            float vv[4] = {v.x, v.y, v.z, v.w};
            int r = rem * 4;
#pragma unroll
            for (int x = 0; x < 4; ++x) {
                int rr = r + x, i = rr / 7, s = rr - i * 7;
                rbf_s[e][i * 8 + s] = bf16rne(vv[x]);
            }
        }
    }

    // phase 1: sk[s][q] = sum_k sph * m  (thread: edge, embs oct*8..+7)
    float sk[NSPH][8];
#pragma unroll
    for (int s = 0; s < NSPH; ++s)
#pragma unroll
        for (int q = 0; q < 8; ++q) sk[s][q] = 0.f;

    for (int kp = 0; kp < 8; ++kp) {
        __syncthreads();
        // stage 2 k-planes of m (zero-filled when t<0), coalesced
#pragma unroll
        for (int c = 0; c < 4; ++c) {
            int f = c * 256 + tid;               // 0..1023 float4 slots
            int kk = f >> 9, rem = f & 511;
            int e = rem >> 5, c4 = (rem & 31) << 2;
            int t = inv_s[e * 16 + 2 * kp + kk];
            float4 v = make_float4(0.f, 0.f, 0.f, 0.f);
            if (t >= 0) v = *(const float4*)(m + (size_t)t * EMB + c4);
            *(float4*)&m_s[kk][e][c4] = v;
        }
        __syncthreads();
#pragma unroll
        for (int kk = 0; kk < 2; ++kk) {
            int k = 2 * kp + kk;
            float mv[8];
            *(float4*)&mv[0] = *(const float4*)&m_s[kk][edge][oct * 8];
            *(float4*)&mv[4] = *(const float4*)&m_s[kk][edge][oct * 8 + 4];
            float cs[NSPH];
#pragma unroll
            for (int s = 0; s < NSPH; ++s) cs[s] = sph_s[s * 16 + k][edge];
#pragma unroll
            for (int s = 0; s < NSPH; ++s)
#pragma unroll
                for (int q = 0; q < 8; ++q)
                    sk[s][q] = fmaf(cs[s], mv[q], sk[s][q]);
        }
    }

    // phase 2: A[edge][i][oct*8+j] = sum_s rbf*sk, bf16, frag-order, 1KB wave stores
    const size_t obase = (size_t)mt * 256;
    const int w = oct >> 2;
    const int l = tid & 63;
#pragma unroll 4
    for (int i = 0; i < INTERM; ++i) {
        uint4 r4 = *(const uint4*)&rbf_s[edge][i * 8];
        float rv[NSPH];
        rv[0] = __uint_as_float(r4.x << 16);
        rv[1] = __uint_as_float(r4.x & 0xffff0000u);
        rv[2] = __uint_as_float(r4.y << 16);
        rv[3] = __uint_as_float(r4.y & 0xffff0000u);
        rv[4] = __uint_as_float(r4.z << 16);
        rv[5] = __uint_as_float(r4.z & 0xffff0000u);
        rv[6] = __uint_as_float(r4.w << 16);
        unsigned pk[4];
#pragma unroll
        for (int jj = 0; jj < 4; ++jj) {
            float v0 = 0.f, v1 = 0.f;
#pragma unroll
            for (int s = 0; s < NSPH; ++s) {
                v0 = fmaf(rv[s], sk[s][2 * jj], v0);
                v1 = fmaf(rv[s], sk[s][2 * jj + 1], v1);
            }
            pk[jj] = bf16pair(v0, v1);
        }
        aw[(obase + (size_t)(i * 4 + w)) * 64 + l] = make_uint4(pk[0], pk[1], pk[2], pk[3]);
    }
}

// gemm: split-K. block = (mc, slice): 4 m-tiles (64 edges) x N=128 x 64 ksteps.
// waves: wm = wid&1 -> m-tile pair, wn = wid>>1 -> 64-col half.
template<bool ATOMIC>
__global__ __launch_bounds__(256)
void gemm_k(const uint4* __restrict__ afrag, const uint4* __restrict__ w2f,
            float* __restrict__ P) {
    __shared__ uint4 buf[4 * 8 * 64];    // 32 KB: [tile][ksl][lane]

    const int tid  = threadIdx.x;
    const int lane = tid & 63, wid = tid >> 6;
    const int slice = blockIdx.x & 3;
    const int mc    = blockIdx.x >> 2;
    const int wm = wid & 1, wn = wid >> 1;

    int srcTile[4];
#pragma unroll
    for (int t = 0; t < 4; ++t) {
        int mt = mc * 4 + t;
        srcTile[t] = mt < MT_TOTAL ? mt : MT_TOTAL - 1;
    }

    floatx4 acc[2][4];
#pragma unroll
    for (int h = 0; h < 2; ++h)
#pragma unroll
        for (int q = 0; q < 4; ++q) acc[h][q] = (floatx4){0.f, 0.f, 0.f, 0.f};

    for (int ch = 0; ch < 8; ++ch) {
        const int ks0 = slice * 64 + ch * 8;
        __syncthreads();
#pragma unroll
        for (int c = 0; c < 8; ++c) {
            int f = c * 256 + tid;           // 0..2047
            int tle = f >> 9, rem = f & 511; // rem = ksl*64 + srcLane
            size_t src = ((size_t)srcTile[tle] * 256 + ks0 + (rem >> 6)) * 64 + (rem & 63);
            gload_lds16(afrag + src, &buf[f]);
        }
        __syncthreads();
#pragma unroll
        for (int ksl = 0; ksl < 8; ++ksl) {
            short8 a0 = __builtin_bit_cast(short8, buf[(2 * wm) * 512 + ksl * 64 + lane]);
            short8 a1 = __builtin_bit_cast(short8, buf[(2 * wm + 1) * 512 + ksl * 64 + lane]);
#pragma unroll
            for (int q = 0; q < 4; ++q) {
                int nt = wn * 4 + q;
                short8 b = __builtin_bit_cast(short8,
                            w2f[((size_t)nt * KSTEPS + ks0 + ksl) * 64 + lane]);
                acc[0][q] = __builtin_amdgcn_mfma_f32_16x16x32_bf16(a0, b, acc[0][q], 0, 0, 0);
                acc[1][q] = __builtin_amdgcn_mfma_f32_16x16x32_bf16(a1, b, acc[1][q], 0, 0, 0);
            }
        }
    }

    // epilogue: C/D col = lane&15, row = (lane>>4)*4 + r
    const int col = lane & 15, r0 = (lane >> 4) * 4;
#pragma unroll
    for (int h = 0; h < 2; ++h) {
        int mt = mc * 4 + 2 * wm + h;
        if (mt < MT_TOTAL) {
#pragma unroll
            for (int q = 0; q < 4; ++q) {
                int o = wn * 64 + q * 16 + col;
#pragma unroll
                for (int r = 0; r < 4; ++r) {
                    size_t eidx = (size_t)mt * 16 + r0 + r;
                    if (ATOMIC)
                        atomicAdd(&P[eidx * UNITS + o], acc[h][q][r]);
                    else
                        P[((size_t)slice * PROWS + eidx) * UNITS + o] = acc[h][q][r];
                }
            }
        }
    }
}

__global__ void reduce_p(const float4* __restrict__ P, float4* __restrict__ out) {
    int idx = blockIdx.x * 256 + threadIdx.x;
    if (idx < NEDGES * 32) {
        const size_t S = (size_t)PROWS * 32;
        float4 a = P[idx], b = P[idx + S], c = P[idx + 2 * S], d = P[idx + 3 * S];
        out[idx] = make_float4(a.x + b.x + c.x + d.x, a.y + b.y + c.y + d.y,
                               a.z + b.z + c.z + d.z, a.w + b.w + c.w + d.w);
    }
}

extern "C" void kernel_launch(void* const* d_in, const int* in_sizes, int n_in,
                              void* d_out, int out_size, void* d_ws, size_t ws_size,
                              hipStream_t stream) {
    const float* rbf = (const float*)d_in[0];
    const float* sph = (const float*)d_in[1];
    const float* m   = (const float*)d_in[2];
    const float* w   = (const float*)d_in[3];
    const int*   idr = (const int*)d_in[4];
    const int*   kix = (const int*)d_in[5];
    float* out = (float*)d_out;

    // ws: inv | w2f | P (split-K partials) | A    (fallback: inv | w2f | A, atomics)
    int*   inv = (int*)d_ws;
    uint4* w2f = (uint4*)((char*)d_ws + 0x140000);
    const size_t OFF_P   = 0x340000;
    const size_t P_BYTES = (size_t)NSLICE * PROWS * UNITS * 4;   // 41,025,536
    const size_t OFF_AP  = (OFF_P + P_BYTES + 255) & ~(size_t)255;
    const size_t A_BYTES = (size_t)MT_TOTAL * KSTEPS * 64 * 16;  // 327,680,000
    const bool useP = ws_size >= OFF_AP + A_BYTES;

    uint4* A = (uint4*)((char*)d_ws + (useP ? OFF_AP : OFF_P));
    float* P = (float*)((char*)d_ws + OFF_P);

    hipMemsetAsync(inv, 0xFF, (size_t)NEDGES * KMAX * sizeof(int), stream);
    scatter_inv<<<NTRIP / 256, 256, 0, stream>>>(idr, kix, inv);
    build_w2f<<<512, 256, 0, stream>>>(w, w2f);
    build_a<<<MT_TOTAL, 256, 0, stream>>>(rbf, sph, m, inv, A);

    if (useP) {
        gemm_k<false><<<MCHUNKS * NSLICE, 256, 0, stream>>>(A, w2f, P);
        reduce_p<<<(NEDGES * 32 + 255) / 256, 256, 0, stream>>>((const float4*)P, (float4*)out);
    } else {
        hipMemsetAsync(out, 0, (size_t)out_size * sizeof(float), stream);
        gemm_k<true><<<MCHUNKS * NSLICE, 256, 0, stream>>>(A, w2f, out);
    }
}

// Round 4
// 406.573 us; speedup vs baseline: 1.3838x; 1.3838x over previous
//
#include <hip/hip_runtime.h>

#define NEDGES 20000
#define KMAX 16
#define NTRIP (NEDGES*KMAX)
#define EMB 128
#define INTERM 64
#define NSPH 7
#define UNITS 128
#define KSTEPS 256               // K = 8192 / 32

typedef __attribute__((ext_vector_type(8))) short short8;
typedef __attribute__((ext_vector_type(4))) float floatx4;

__device__ __forceinline__ unsigned bf16pair(float a, float b) {
    unsigned ua = __float_as_uint(a), ub = __float_as_uint(b);
    ua = (ua + 0x7fffu + ((ua >> 16) & 1u)) >> 16;
    ub = (ub + 0x7fffu + ((ub >> 16) & 1u)) & 0xffff0000u;
    return ua | ub;
}
__device__ __forceinline__ unsigned short bf16rne(float a) {
    unsigned u = __float_as_uint(a);
    return (unsigned short)((u + 0x7fffu + ((u >> 16) & 1u)) >> 16);
}

__global__ void scatter_inv(const int* __restrict__ idr, const int* __restrict__ kix,
                            int* __restrict__ inv) {
    int t = blockIdx.x * 256 + threadIdx.x;
    if (t < NTRIP) {
        int e = idr[t], k = kix[t];
        if ((unsigned)e < NEDGES && (unsigned)k < KMAX)
            inv[e * KMAX + k] = t;
    }
}

// weight (emb, interm, o) fp32 -> bf16 MFMA B-fragment order.
// uint4 idx = (nt*256 + ks)*64 + lane; elem j: k = ks*32 + (lane>>4)*8 + j,
// o = nt*16 + (lane&15); k = i*128 + emb.
__global__ void build_w2f(const float* __restrict__ w, uint4* __restrict__ w2f) {
    int idx  = blockIdx.x * 256 + threadIdx.x;
    int lane = idx & 63;
    int ks   = (idx >> 6) & 255;
    int nt   = idx >> 14;
    int o  = nt * 16 + (lane & 15);
    int kb = ks * 32 + (lane >> 4) * 8;
    unsigned pk[4];
#pragma unroll
    for (int jj = 0; jj < 4; ++jj) {
        int k0 = kb + 2 * jj;
        int i0 = k0 >> 7, em0 = k0 & 127;
        int i1 = (k0 + 1) >> 7, em1 = (k0 + 1) & 127;
        float f0 = w[((size_t)em0 * INTERM + i0) * UNITS + o];
        float f1 = w[((size_t)em1 * INTERM + i1) * UNITS + o];
        pk[jj] = bf16pair(f0, f1);
    }
    w2f[idx] = make_uint4(pk[0], pk[1], pk[2], pk[3]);
}

// build_sumk: block = 16 edges. sumk[e][s][emb] bf16, stored as uint4:
//   sumk[(e*7 + s)*16 + oct], oct = emb octet (8 bf16 = 16 B).
// thread: edge = tid>>4, oct = tid&15.
__global__ __launch_bounds__(256)
void build_sumk(const float* __restrict__ sph, const float* __restrict__ m,
                const int* __restrict__ inv, uint4* __restrict__ sumk) {
    __shared__ float m_s[2][16][128];   // 16 KB
    __shared__ float sph_s[16 * 112];   // 7 KB
    __shared__ int inv_s[256];

    const int tid = threadIdx.x;
    const size_t e0 = (size_t)blockIdx.x * 16;
    const int edge = tid >> 4, oct = tid & 15;

    inv_s[tid] = inv[e0 * 16 + tid];
    for (int j = tid; j < 16 * 112; j += 256) sph_s[j] = sph[e0 * 112 + j];

    float sk[NSPH][8];
#pragma unroll
    for (int s = 0; s < NSPH; ++s)
#pragma unroll
        for (int q = 0; q < 8; ++q) sk[s][q] = 0.f;

    for (int kp = 0; kp < 8; ++kp) {
        __syncthreads();
        // stage 2 k-planes of m, coalesced (zero-fill for missing triplets)
#pragma unroll
        for (int c = 0; c < 4; ++c) {
            int f = c * 256 + tid;               // 0..1023 float4 slots
            int kk = f >> 9, rem = f & 511;
            int e = rem >> 5, q = rem & 31;
            int t = inv_s[e * 16 + 2 * kp + kk];
            float4 v = make_float4(0.f, 0.f, 0.f, 0.f);
            if (t >= 0) v = ((const float4*)(m + (size_t)t * EMB))[q];
            ((float4*)m_s[kk][e])[q] = v;
        }
        __syncthreads();
#pragma unroll
        for (int kk = 0; kk < 2; ++kk) {
            int k = 2 * kp + kk;
            float mv[8];
            *(float4*)&mv[0] = ((const float4*)m_s[kk][edge])[oct * 2];
            *(float4*)&mv[4] = ((const float4*)m_s[kk][edge])[oct * 2 + 1];
            float cs[NSPH];
#pragma unroll
            for (int s = 0; s < NSPH; ++s) cs[s] = sph_s[edge * 112 + s * 16 + k];
#pragma unroll
            for (int s = 0; s < NSPH; ++s)
#pragma unroll
                for (int q = 0; q < 8; ++q)
                    sk[s][q] = fmaf(cs[s], mv[q], sk[s][q]);
        }
    }

#pragma unroll
    for (int s = 0; s < NSPH; ++s)
        sumk[((e0 + edge) * 7 + s) * 16 + oct] = make_uint4(
            bf16pair(sk[s][0], sk[s][1]), bf16pair(sk[s][2], sk[s][3]),
            bf16pair(sk[s][4], sk[s][5]), bf16pair(sk[s][6], sk[s][7]));
}

// fused_gemm: block = 32 edges x N=128 x full K. 512 threads (8 waves, wave = nt).
// Per-thread sum_k slice (edge e=tid>>4, embs oct*8..+7) held in 56 VGPRs.
// K iterated as 64 chunks of one interm i (4 ksteps); A-frags built into LDS
// double buffer (one barrier per chunk); w2f B-frags register-prefetched.
__global__ __launch_bounds__(512, 4)
void fused_gemm(const float* __restrict__ rbf, const uint4* __restrict__ sumk,
                const uint4* __restrict__ w2f, float* __restrict__ out) {
    __shared__ unsigned short rbf_s[32][528];   // 33792 B (16B-aligned rows)
    __shared__ uint4 a_s[2][8 * 65];            // 16640 B, row stride 65

    const int tid = threadIdx.x;
    const size_t e0 = (size_t)blockIdx.x * 32;
    const int lane = tid & 63, wid = tid >> 6;   // wid = nt 0..7
    const int e = tid >> 4, oct = tid & 15;      // e 0..31
    const int mt = e >> 4;
    const int arow = mt * 4 + (oct >> 2);        // frag row within chunk (0..7)
    const int slot = (oct & 3) * 16 + (e & 15);  // lane within fragment

    // stage rbf tile -> bf16 LDS, rows padded to 8 per i
    {
        const float4* rg = (const float4*)(rbf + e0 * 448);
        for (int f = tid; f < 3584; f += 512) {
            int ee = f / 112, idx = f - ee * 112;
            float4 v = rg[f];
            float vv[4] = {v.x, v.y, v.z, v.w};
            int rr = idx * 4;
#pragma unroll
            for (int x = 0; x < 4; ++x) {
                int r2 = rr + x, i = r2 / 7, s = r2 - i * 7;
                rbf_s[ee][i * 8 + s] = bf16rne(vv[x]);
            }
        }
    }

    // per-thread sum_k -> 56 fp32 regs (coalesced global reads, no LDS)
    float skf[NSPH][8];
    {
        const uint4* sp = sumk + (e0 + e) * 112 + oct;
#pragma unroll
        for (int s = 0; s < NSPH; ++s) {
            uint4 u = sp[s * 16];
            unsigned uu[4] = {u.x, u.y, u.z, u.w};
#pragma unroll
            for (int h = 0; h < 4; ++h) {
                skf[s][2 * h]     = __uint_as_float(uu[h] << 16);
                skf[s][2 * h + 1] = __uint_as_float(uu[h] & 0xffff0000u);
            }
        }
    }
    __syncthreads();

    auto buildChunk = [&](int i, uint4* dst) {
        uint4 r4 = *(const uint4*)&rbf_s[e][i * 8];
        float rv[NSPH];
        rv[0] = __uint_as_float(r4.x << 16);
        rv[1] = __uint_as_float(r4.x & 0xffff0000u);
        rv[2] = __uint_as_float(r4.y << 16);
        rv[3] = __uint_as_float(r4.y & 0xffff0000u);
        rv[4] = __uint_as_float(r4.z << 16);
        rv[5] = __uint_as_float(r4.z & 0xffff0000u);
        rv[6] = __uint_as_float(r4.w << 16);
        float v[8];
#pragma unroll
        for (int q = 0; q < 8; ++q) v[q] = rv[0] * skf[0][q];
#pragma unroll
        for (int s = 1; s < NSPH; ++s)
#pragma unroll
            for (int q = 0; q < 8; ++q) v[q] = fmaf(rv[s], skf[s][q], v[q]);
        dst[arow * 65 + slot] = make_uint4(bf16pair(v[0], v[1]), bf16pair(v[2], v[3]),
                                           bf16pair(v[4], v[5]), bf16pair(v[6], v[7]));
    };

    floatx4 acc[2] = {{0.f, 0.f, 0.f, 0.f}, {0.f, 0.f, 0.f, 0.f}};
    uint4 wf[4];
    const uint4* wbase = w2f + ((size_t)wid * KSTEPS) * 64 + lane;
#pragma unroll
    for (int ksl = 0; ksl < 4; ++ksl) wf[ksl] = wbase[(size_t)ksl * 64];

    buildChunk(0, a_s[0]);
    __syncthreads();

    for (int c = 0; c < 64; ++c) {
        const int cur = c & 1, nxt = cur ^ 1;
        if (c < 63) buildChunk(c + 1, a_s[nxt]);
#pragma unroll
        for (int ksl = 0; ksl < 4; ++ksl) {
            short8 a0 = __builtin_bit_cast(short8, a_s[cur][ksl * 65 + lane]);
            short8 a1 = __builtin_bit_cast(short8, a_s[cur][(4 + ksl) * 65 + lane]);
            short8 b  = __builtin_bit_cast(short8, wf[ksl]);
            acc[0] = __builtin_amdgcn_mfma_f32_16x16x32_bf16(a0, b, acc[0], 0, 0, 0);
            acc[1] = __builtin_amdgcn_mfma_f32_16x16x32_bf16(a1, b, acc[1], 0, 0, 0);
        }
        const int kn = (c < 63 ? c + 1 : 63) * 4;   // prefetch next chunk's B-frags
#pragma unroll
        for (int ksl = 0; ksl < 4; ++ksl) wf[ksl] = wbase[(size_t)(kn + ksl) * 64];
        __syncthreads();
    }

    // epilogue: C/D col = lane&15, row = (lane>>4)*4 + r
    const int col = lane & 15, r0 = (lane >> 4) * 4;
#pragma unroll
    for (int h = 0; h < 2; ++h) {
        size_t ebase = e0 + (size_t)h * 16 + r0;
#pragma unroll
        for (int r = 0; r < 4; ++r)
            out[(ebase + r) * UNITS + wid * 16 + col] = acc[h][r];
    }
}

extern "C" void kernel_launch(void* const* d_in, const int* in_sizes, int n_in,
                              void* d_out, int out_size, void* d_ws, size_t ws_size,
                              hipStream_t stream) {
    const float* rbf = (const float*)d_in[0];
    const float* sph = (const float*)d_in[1];
    const float* m   = (const float*)d_in[2];
    const float* w   = (const float*)d_in[3];
    const int*   idr = (const int*)d_in[4];
    const int*   kix = (const int*)d_in[5];
    float* out = (float*)d_out;

    // ws: inv (1.28 MB, pad to 0x140000) | w2f (2 MB) | sumk (35.84 MB)
    int*   inv  = (int*)d_ws;
    uint4* w2f  = (uint4*)((char*)d_ws + 0x140000);
    uint4* sumk = (uint4*)((char*)d_ws + 0x340000);

    hipMemsetAsync(inv, 0xFF, (size_t)NEDGES * KMAX * sizeof(int), stream);
    scatter_inv<<<NTRIP / 256, 256, 0, stream>>>(idr, kix, inv);
    build_w2f<<<512, 256, 0, stream>>>(w, w2f);
    build_sumk<<<NEDGES / 16, 256, 0, stream>>>(sph, m, inv, sumk);
    fused_gemm<<<NEDGES / 32, 512, 0, stream>>>(rbf, sumk, w2f, out);
}